// Round 1
// baseline (1488.568 us; speedup 1.0000x reference)
//
#include <hip/hip_runtime.h>

typedef _Float16 f16;
typedef _Float16 half8 __attribute__((ext_vector_type(8)));
typedef float f32x4 __attribute__((ext_vector_type(4)));

__device__ __forceinline__ void gl_lds16(const void* g, void* l) {
  __builtin_amdgcn_global_load_lds(
      (__attribute__((address_space(1))) void*)(size_t)g,
      (__attribute__((address_space(3))) void*)l, 16, 0, 0);
}

// ---------------------------------------------------------------------------
// GEMM: C[M,N] = A[M,KP] * Bw[N,KP]^T (+bias). 128x128 tile, BK=64, 4 waves.
// EPI 0: f16 out + column stats partials (pre-BN layer)
// EPI 1: f16 out
// EPI 2: f32 out, cols masked to Ncols (writes to d_out)
// ---------------------------------------------------------------------------
template <int EPI>
__global__ __launch_bounds__(256) void gemm_k(
    const f16* __restrict__ A, const f16* __restrict__ Bw, int Ksteps, int KP,
    void* __restrict__ outp, int ldOut, int Ncols,
    const float* __restrict__ bias, float2* __restrict__ partial) {
  __shared__ char smem[33792];
  f16* sA = (f16*)smem;               // 16 KB : [128][64] f16
  f16* sB = (f16*)(smem + 16384);     // 16 KB : [128][64] f16
  float* sC = (float*)smem;           // 33792 B : [64][132] f32 (epilogue)

  const int t = threadIdx.x;
  const int wave = t >> 6;
  const int lane = t & 63;
  const int wr = wave >> 1, wc = wave & 1;
  const int l16 = lane & 15, lg = lane >> 4;
  const int m0 = blockIdx.y * 128;
  const int n0 = blockIdx.x * 128;

  f32x4 acc[4][4] = {};

  const int rA = t >> 3;                       // 0..31
  const size_t stepR = (size_t)32 * KP * 2;    // 32 rows
  const char* gA = (const char*)A + ((size_t)(m0 + rA) * KP) * 2 + (t & 7) * 16;
  const char* gB = (const char*)Bw + ((size_t)(n0 + rA) * KP) * 2 + (t & 7) * 16;
  char* lA = smem + t * 16;
  char* lB = smem + 16384 + t * 16;

  for (int kt = 0; kt < Ksteps; ++kt) {
    const char* pA = gA + (size_t)kt * 128;
    const char* pB = gB + (size_t)kt * 128;
#pragma unroll
    for (int r = 0; r < 4; ++r) {
      gl_lds16(pA, lA + r * 4096);
      gl_lds16(pB, lB + r * 4096);
      pA += stepR;
      pB += stepR;
    }
    __syncthreads();
#pragma unroll
    for (int kk = 0; kk < 2; ++kk) {
      const int ko = kk * 32 + lg * 8;
      half8 af[4], bf[4];
#pragma unroll
      for (int m = 0; m < 4; ++m)
        af[m] = *(const half8*)(sA + (wr * 64 + m * 16 + l16) * 64 + ko);
#pragma unroll
      for (int n = 0; n < 4; ++n)
        bf[n] = *(const half8*)(sB + (wc * 64 + n * 16 + l16) * 64 + ko);
#pragma unroll
      for (int m = 0; m < 4; ++m)
#pragma unroll
        for (int n = 0; n < 4; ++n)
          acc[m][n] = __builtin_amdgcn_mfma_f32_16x16x32_f16(af[m], bf[n], acc[m][n], 0, 0, 0);
    }
    __syncthreads();
  }

  // ---- epilogue: restage f32 tile through LDS (stride 132), coalesced out ----
  float biasv[4];
#pragma unroll
  for (int n = 0; n < 4; ++n) {
    int c = n0 + wc * 64 + n * 16 + l16;
    biasv[n] = (bias != nullptr && c < Ncols) ? bias[c] : 0.f;
  }

  float csum = 0.f, csq = 0.f;

#pragma unroll
  for (int h = 0; h < 2; ++h) {
    __syncthreads();
    if (wr == h) {
#pragma unroll
      for (int m = 0; m < 4; ++m)
#pragma unroll
        for (int n = 0; n < 4; ++n)
#pragma unroll
          for (int r = 0; r < 4; ++r) {
            int lr = m * 16 + lg * 4 + r;  // C/D: row=(lane>>4)*4+reg, col=lane&15
            sC[lr * 132 + wc * 64 + n * 16 + l16] = acc[m][n][r] + biasv[n];
          }
    }
    __syncthreads();
    const int lr = t >> 2;
    const int cs = (t & 3) * 32;
    const float* src = sC + lr * 132 + cs;
    const int row = m0 + h * 64 + lr;
    if constexpr (EPI == 2) {
      float* rowp = (float*)outp + (size_t)row * ldOut;
#pragma unroll
      for (int j = 0; j < 32; j += 4) {
        int c = n0 + cs + j;
        if (c + 3 < Ncols) {
          *(f32x4*)(rowp + c) = *(const f32x4*)(src + j);
        } else {
#pragma unroll
          for (int e = 0; e < 4; ++e)
            if (c + e < Ncols) rowp[c + e] = src[j + e];
        }
      }
    } else {
      f16* dst = (f16*)outp + (size_t)row * ldOut + n0 + cs;
#pragma unroll
      for (int j = 0; j < 32; j += 8) {
        f32x4 v0 = *(const f32x4*)(src + j);
        f32x4 v1 = *(const f32x4*)(src + j + 4);
        half8 hv;
#pragma unroll
        for (int e = 0; e < 4; ++e) {
          hv[e] = (f16)v0[e];
          hv[4 + e] = (f16)v1[e];
        }
        *(half8*)(dst + j) = hv;
      }
    }
    if constexpr (EPI == 0) {
      if (t < 128) {
        for (int r2 = 0; r2 < 64; ++r2) {
          float v = sC[r2 * 132 + t];
          csum += v;
          csq += v * v;
        }
      }
    }
  }
  if constexpr (EPI == 0) {
    if (t < 128) partial[(size_t)blockIdx.y * 1024 + n0 + t] = make_float2(csum, csq);
  }
}

// ---------------------------------------------------------------------------
__global__ void bn_fin_k(const float2* __restrict__ partial, int mtiles,
                         const float* __restrict__ g, const float* __restrict__ beta,
                         float2* __restrict__ ss, float invB) {
  const int c = blockIdx.x * 256 + threadIdx.x;  // grid 4 -> 1024 cols
  float s = 0.f, q = 0.f;
  for (int mt = 0; mt < mtiles; ++mt) {
    float2 v = partial[(size_t)mt * 1024 + c];
    s += v.x;
    q += v.y;
  }
  float m = s * invB;
  float var = q * invB - m * m;
  float sc = rsqrtf(var + 1e-3f) * g[c];
  ss[c] = make_float2(sc, beta[c] - m * sc);
}

__global__ void bn_apply_k(f16* __restrict__ Y, const float2* __restrict__ ss, int total8) {
  int i = blockIdx.x * blockDim.x + threadIdx.x;
  const int stride = gridDim.x * blockDim.x;
  for (; i < total8; i += stride) {
    half8 v = *(half8*)(Y + (size_t)i * 8);
    const int c0 = (i & 127) * 8;
#pragma unroll
    for (int j = 0; j < 8; ++j) {
      float2 sv = ss[c0 + j];
      float z = fmaxf((float)v[j] * sv.x + sv.y, 0.f);
      v[j] = (f16)z;
    }
    *(half8*)(Y + (size_t)i * 8) = v;
  }
}

// ---------------------------------------------------------------------------
__global__ void cvt_w_k(const float* __restrict__ W, f16* __restrict__ Wp, int N, int K, int KP) {
  const int k = blockIdx.x * 256 + threadIdx.x;
  const int n = blockIdx.y;
  if (k >= KP) return;
  float v = (n < N && k < K) ? W[(size_t)n * K + k] : 0.f;
  Wp[(size_t)n * KP + k] = (f16)v;
}

__global__ void cvt_in_k(const float* __restrict__ ip, const float* __restrict__ in_,
                         const float* __restrict__ tg, f16* __restrict__ Ap,
                         f16* __restrict__ An, f16* __restrict__ Am) {
  const int col = blockIdx.x * 256 + threadIdx.x;
  const int row = blockIdx.y;
  if (col >= 320) return;
  const size_t o = (size_t)row * 320 + col;
  float vp = 0.f, vn = 0.f, vm = 0.f;
  if (col < 300) {
    vp = ip[(size_t)row * 300 + col];
    vn = in_[(size_t)row * 300 + col];
  }
  if (col >= 10 && col < 310) vm = tg[(size_t)row * 300 + (col - 10)];
  Ap[o] = (f16)vp;
  An[o] = (f16)vn;
  Am[o] = (f16)vm;
}

// --------------------------- loc branch ------------------------------------
__global__ void loc_stats_k(const float* __restrict__ lat, const float* __restrict__ lon,
                            const float* __restrict__ Wloc, const float* __restrict__ bloc,
                            float* __restrict__ partial) {
  const int t = threadIdx.x;
  const int row = blockIdx.x * 256 + t;
  float la = lat[row], lo = lon[row];
  float s[10], q[10];
#pragma unroll
  for (int j = 0; j < 10; ++j) {
    float y = la * Wloc[j * 2] + lo * Wloc[j * 2 + 1] + bloc[j];
    s[j] = y;
    q[j] = y * y;
  }
#pragma unroll
  for (int j = 0; j < 10; ++j)
    for (int off = 32; off; off >>= 1) {
      s[j] += __shfl_xor(s[j], off);
      q[j] += __shfl_xor(q[j], off);
    }
  __shared__ float red[4][20];
  const int wave = t >> 6, lane = t & 63;
  if (lane == 0) {
#pragma unroll
    for (int j = 0; j < 10; ++j) {
      red[wave][j] = s[j];
      red[wave][10 + j] = q[j];
    }
  }
  __syncthreads();
  if (t < 20) partial[blockIdx.x * 20 + t] = red[0][t] + red[1][t] + red[2][t] + red[3][t];
}

__global__ void loc_fin_k(const float* __restrict__ partial, int nblk,
                          const float* __restrict__ g, const float* __restrict__ beta,
                          float2* __restrict__ ss, float invB) {
  int t = threadIdx.x;
  if (t < 10) {
    float s = 0.f, q = 0.f;
    for (int b = 0; b < nblk; ++b) {
      s += partial[b * 20 + t];
      q += partial[b * 20 + 10 + t];
    }
    float m = s * invB;
    float var = q * invB - m * m;
    float sc = rsqrtf(var + 1e-3f) * g[t];
    ss[t] = make_float2(sc, beta[t] - m * sc);
  }
}

__global__ void loc_write_k(const float* __restrict__ lat, const float* __restrict__ lon,
                            const float* __restrict__ Wloc, const float* __restrict__ bloc,
                            const float2* __restrict__ ss, f16* __restrict__ Am) {
  const int row = blockIdx.x * 256 + threadIdx.x;
  float la = lat[row], lo = lon[row];
  f16* dst = Am + (size_t)row * 320;
#pragma unroll
  for (int j = 0; j < 10; ++j) {
    float y = la * Wloc[j * 2] + lo * Wloc[j * 2 + 1] + bloc[j];
    float2 sv = ss[j];
    dst[j] = (f16)fmaxf(y * sv.x + sv.y, 0.f);
  }
}

// --------------------------- count -----------------------------------------
__global__ void count_k(const float* __restrict__ P, const float* __restrict__ Nn,
                        const float* __restrict__ Aa, int B, int* __restrict__ cnt) {
  const int gw = (blockIdx.x * blockDim.x + threadIdx.x) >> 6;
  const int lane = threadIdx.x & 63;
  const int nw = (gridDim.x * blockDim.x) >> 6;
  int local = 0;
  for (int row = gw; row < B; row += nw) {
    const float* ar = Aa + (size_t)row * 300;
    const float* pr = P + (size_t)row * 300;
    const float* nr = Nn + (size_t)row * 300;
    float sp = 0.f, sn = 0.f;
    for (int e = lane; e < 300; e += 64) {
      float av = ar[e];
      float d1 = av - pr[e] + 1e-6f;
      float d2 = av - nr[e] + 1e-6f;
      sp += d1 * d1;
      sn += d2 * d2;
    }
#pragma unroll
    for (int off = 32; off; off >>= 1) {
      sp += __shfl_xor(sp, off);
      sn += __shfl_xor(sn, off);
    }
    if (lane == 0 && (sqrtf(sn) - sqrtf(sp) > 0.1f)) ++local;
  }
  if (lane == 0 && local) atomicAdd(cnt, local);
}

__global__ void zero_i32(int* p) {
  if (threadIdx.x == 0 && blockIdx.x == 0) *p = 0;
}
__global__ void write_cnt_k(const int* c, float* o) {
  if (threadIdx.x == 0 && blockIdx.x == 0) *o = (float)(*c);
}

// ---------------------------------------------------------------------------
extern "C" void kernel_launch(void* const* d_in, const int* in_sizes, int n_in,
                              void* d_out, int out_size, void* d_ws, size_t ws_size,
                              hipStream_t stream) {
  const float* img_p = (const float*)d_in[0];
  const float* img_n = (const float*)d_in[1];
  const float* tag = (const float*)d_in[2];
  const float* lat = (const float*)d_in[3];
  const float* lon = (const float*)d_in[4];
  const float* Wi1 = (const float*)d_in[5];
  const float* bi1 = (const float*)d_in[6];
  const float* gi1 = (const float*)d_in[7];
  const float* bti1 = (const float*)d_in[8];
  const float* Wi2 = (const float*)d_in[9];
  const float* bi2 = (const float*)d_in[10];
  const float* Wi3 = (const float*)d_in[11];
  const float* bi3 = (const float*)d_in[12];
  const float* Wloc = (const float*)d_in[13];
  const float* bloc = (const float*)d_in[14];
  const float* gloc = (const float*)d_in[15];
  const float* btloc = (const float*)d_in[16];
  const float* Wm1 = (const float*)d_in[17];
  const float* bm1 = (const float*)d_in[18];
  const float* gm1 = (const float*)d_in[19];
  const float* btm1 = (const float*)d_in[20];
  const float* Wm2 = (const float*)d_in[21];
  const float* bm2 = (const float*)d_in[22];
  const float* gm2 = (const float*)d_in[23];
  const float* btm2 = (const float*)d_in[24];
  const float* Wm3 = (const float*)d_in[25];
  const float* bm3 = (const float*)d_in[26];
  const float* gm3 = (const float*)d_in[27];
  const float* btm3 = (const float*)d_in[28];
  const float* Wm4 = (const float*)d_in[29];
  const float* bm4 = (const float*)d_in[30];

  const int B = in_sizes[3];  // lat has B elements
  const int MT = B / 128;
  float* out = (float*)d_out;
  float* outP = out;
  float* outN = out + (size_t)B * 300;
  float* outA = out + (size_t)2 * B * 300;
  float* outC = out + (size_t)3 * B * 300;

  char* w = (char*)d_ws;
  auto alloc = [&](size_t bytes) {
    char* p = w;
    w += (bytes + 255) & ~(size_t)255;
    return p;
  };
  f16* Wi1p = (f16*)alloc((size_t)1024 * 320 * 2);
  f16* Wi2p = (f16*)alloc((size_t)1024 * 1024 * 2);
  f16* Wi3p = (f16*)alloc((size_t)384 * 1024 * 2);
  f16* Wm1p = (f16*)alloc((size_t)1024 * 320 * 2);
  f16* Wm2p = (f16*)alloc((size_t)1024 * 1024 * 2);
  f16* Wm3p = (f16*)alloc((size_t)1024 * 1024 * 2);
  f16* Wm4p = (f16*)alloc((size_t)384 * 1024 * 2);
  f16* Ap = (f16*)alloc((size_t)B * 320 * 2);
  f16* An = (f16*)alloc((size_t)B * 320 * 2);
  f16* Am = (f16*)alloc((size_t)B * 320 * 2);
  f16* ACT0 = (f16*)alloc((size_t)B * 1024 * 2);
  f16* ACT1 = (f16*)alloc((size_t)B * 1024 * 2);
  float2* part = (float2*)alloc((size_t)MT * 1024 * 8);
  float2* ss = (float2*)alloc(1024 * 8);
  float* locpart = (float*)alloc((size_t)(B / 256) * 20 * 4);
  float2* locss = (float2*)alloc(16 * 8);
  int* cnt = (int*)alloc(256);
  (void)ws_size;
  (void)out_size;
  (void)n_in;

  const float invB = 1.f / (float)B;

  // weight + input conversion to padded f16
  cvt_w_k<<<dim3(2, 1024), 256, 0, stream>>>(Wi1, Wi1p, 1024, 300, 320);
  cvt_w_k<<<dim3(4, 1024), 256, 0, stream>>>(Wi2, Wi2p, 1024, 1024, 1024);
  cvt_w_k<<<dim3(4, 384), 256, 0, stream>>>(Wi3, Wi3p, 300, 1024, 1024);
  cvt_w_k<<<dim3(2, 1024), 256, 0, stream>>>(Wm1, Wm1p, 1024, 310, 320);
  cvt_w_k<<<dim3(4, 1024), 256, 0, stream>>>(Wm2, Wm2p, 1024, 1024, 1024);
  cvt_w_k<<<dim3(4, 1024), 256, 0, stream>>>(Wm3, Wm3p, 1024, 1024, 1024);
  cvt_w_k<<<dim3(4, 384), 256, 0, stream>>>(Wm4, Wm4p, 300, 1024, 1024);
  cvt_in_k<<<dim3(2, B), 256, 0, stream>>>(img_p, img_n, tag, Ap, An, Am);

  // loc branch (fills Am cols 0..9)
  loc_stats_k<<<dim3(B / 256), 256, 0, stream>>>(lat, lon, Wloc, bloc, locpart);
  loc_fin_k<<<dim3(1), 64, 0, stream>>>(locpart, B / 256, gloc, btloc, locss, invB);
  loc_write_k<<<dim3(B / 256), 256, 0, stream>>>(lat, lon, Wloc, bloc, locss, Am);

  // p branch
  gemm_k<0><<<dim3(8, MT), 256, 0, stream>>>(Ap, Wi1p, 5, 320, ACT0, 1024, 1024, bi1, part);
  bn_fin_k<<<dim3(4), 256, 0, stream>>>(part, MT, gi1, bti1, ss, invB);
  bn_apply_k<<<dim3(2048), 256, 0, stream>>>(ACT0, ss, B * 128);
  gemm_k<1><<<dim3(8, MT), 256, 0, stream>>>(ACT0, Wi2p, 16, 1024, ACT1, 1024, 1024, bi2, nullptr);
  gemm_k<2><<<dim3(3, MT), 256, 0, stream>>>(ACT1, Wi3p, 16, 1024, outP, 300, 300, bi3, nullptr);

  // n branch
  gemm_k<0><<<dim3(8, MT), 256, 0, stream>>>(An, Wi1p, 5, 320, ACT0, 1024, 1024, bi1, part);
  bn_fin_k<<<dim3(4), 256, 0, stream>>>(part, MT, gi1, bti1, ss, invB);
  bn_apply_k<<<dim3(2048), 256, 0, stream>>>(ACT0, ss, B * 128);
  gemm_k<1><<<dim3(8, MT), 256, 0, stream>>>(ACT0, Wi2p, 16, 1024, ACT1, 1024, 1024, bi2, nullptr);
  gemm_k<2><<<dim3(3, MT), 256, 0, stream>>>(ACT1, Wi3p, 16, 1024, outN, 300, 300, bi3, nullptr);

  // mm branch
  gemm_k<0><<<dim3(8, MT), 256, 0, stream>>>(Am, Wm1p, 5, 320, ACT0, 1024, 1024, bm1, part);
  bn_fin_k<<<dim3(4), 256, 0, stream>>>(part, MT, gm1, btm1, ss, invB);
  bn_apply_k<<<dim3(2048), 256, 0, stream>>>(ACT0, ss, B * 128);
  gemm_k<0><<<dim3(8, MT), 256, 0, stream>>>(ACT0, Wm2p, 16, 1024, ACT1, 1024, 1024, bm2, part);
  bn_fin_k<<<dim3(4), 256, 0, stream>>>(part, MT, gm2, btm2, ss, invB);
  bn_apply_k<<<dim3(2048), 256, 0, stream>>>(ACT1, ss, B * 128);
  gemm_k<0><<<dim3(8, MT), 256, 0, stream>>>(ACT1, Wm3p, 16, 1024, ACT0, 1024, 1024, bm3, part);
  bn_fin_k<<<dim3(4), 256, 0, stream>>>(part, MT, gm3, btm3, ss, invB);
  bn_apply_k<<<dim3(2048), 256, 0, stream>>>(ACT0, ss, B * 128);
  gemm_k<2><<<dim3(3, MT), 256, 0, stream>>>(ACT0, Wm4p, 16, 1024, outA, 300, 300, bm4, nullptr);

  // pairwise distances + margin count
  zero_i32<<<1, 64, 0, stream>>>(cnt);
  count_k<<<dim3(256), 256, 0, stream>>>(outP, outN, outA, B, cnt);
  write_cnt_k<<<1, 64, 0, stream>>>(cnt, outC);
}

// Round 2
// 1269.450 us; speedup vs baseline: 1.1726x; 1.1726x over previous
//
#include <hip/hip_runtime.h>

typedef _Float16 f16;
typedef _Float16 half8 __attribute__((ext_vector_type(8)));
typedef float f32x4 __attribute__((ext_vector_type(4)));

__device__ __forceinline__ void gl_lds16(const void* g, void* l) {
  __builtin_amdgcn_global_load_lds(
      (__attribute__((address_space(1))) void*)(size_t)g,
      (__attribute__((address_space(3))) void*)l, 16, 0, 0);
}

// ---------------------------------------------------------------------------
// GEMM: C[M,N] = A'[M,KP] * Bw[N,KP]^T (+bias), A' = optional fused BN+ReLU(A)
// 128x128 tile, BK=64, 4 waves. XCD-chunked block swizzle + LDS XOR swizzle.
// EPI 0: f16 out + column stats partials (pre-BN layer)
// EPI 1: f16 out
// EPI 2: f32 out, cols masked to Ncols (writes to d_out)
// BNA 1: A fragments get y*sc[k]+sh[k], ReLU (consumer-side BatchNorm)
// ---------------------------------------------------------------------------
template <int EPI, int BNA>
__global__ __launch_bounds__(256) void gemm_k(
    const f16* __restrict__ A, const f16* __restrict__ Bw, int Ksteps, int KP,
    void* __restrict__ outp, int ldOut, int Ncols,
    const float* __restrict__ bias, float2* __restrict__ partial,
    const f16* __restrict__ scH, const f16* __restrict__ shH) {
  __shared__ char smem[33792];
  float* sC = (float*)smem;  // epilogue: [64][132] f32

  const int t = threadIdx.x;
  const int lane = t & 63;
  const int wave = t >> 6;
  const int wr = wave >> 1, wc = wave & 1;
  const int l16 = lane & 15, lg = lane >> 4;

  // XCD-chunked bijective swizzle (all launch grids have nwg % 8 == 0)
  int bx = blockIdx.x, by = blockIdx.y;
  {
    const int nwg = gridDim.x * gridDim.y;
    const int wg = bx + gridDim.x * by;
    if ((nwg & 7) == 0) {
      const int cpx = nwg >> 3;
      const int newid = (wg & 7) * cpx + (wg >> 3);
      bx = newid % gridDim.x;
      by = newid / gridDim.x;
    }
  }
  const int m0 = by * 128;
  const int n0 = bx * 128;

  f32x4 acc[4][4] = {};

  const int rA = t >> 3;  // 0..31
  const int seg = (t & 7) ^ (rA & 7);  // pre-swizzled global source (rule #21)
  const size_t stepR = (size_t)32 * KP * 2;
  const char* gA = (const char*)A + ((size_t)(m0 + rA) * KP) * 2 + seg * 16;
  const char* gB = (const char*)Bw + ((size_t)(n0 + rA) * KP) * 2 + seg * 16;
  char* lA = smem + t * 16;
  char* lB = smem + 16384 + t * 16;

  for (int kt = 0; kt < Ksteps; ++kt) {
    const char* pA = gA + (size_t)kt * 128;
    const char* pB = gB + (size_t)kt * 128;
#pragma unroll
    for (int r = 0; r < 4; ++r) {
      gl_lds16(pA, lA + r * 4096);
      gl_lds16(pB, lB + r * 4096);
      pA += stepR;
      pB += stepR;
    }
    __syncthreads();
#pragma unroll
    for (int kk = 0; kk < 2; ++kk) {
      const int segx = (kk << 2) | lg;
      half8 af[4], bf[4];
#pragma unroll
      for (int m = 0; m < 4; ++m) {
        const int row = wr * 64 + m * 16 + l16;
        af[m] = *(const half8*)(smem + row * 128 + ((segx ^ (row & 7)) << 4));
      }
#pragma unroll
      for (int n = 0; n < 4; ++n) {
        const int row = wc * 64 + n * 16 + l16;
        bf[n] = *(const half8*)(smem + 16384 + row * 128 + ((segx ^ (row & 7)) << 4));
      }
      if constexpr (BNA) {
        const int kb = kt * 64 + kk * 32 + lg * 8;
        const half8 scv = *(const half8*)(scH + kb);
        const half8 shv = *(const half8*)(shH + kb);
        const half8 zeroh = {};
#pragma unroll
        for (int m = 0; m < 4; ++m)
          af[m] = __builtin_elementwise_max((half8)(af[m] * scv + shv), zeroh);
      }
#pragma unroll
      for (int m = 0; m < 4; ++m)
#pragma unroll
        for (int n = 0; n < 4; ++n)
          acc[m][n] = __builtin_amdgcn_mfma_f32_16x16x32_f16(af[m], bf[n], acc[m][n], 0, 0, 0);
    }
    __syncthreads();
  }

  // ---- epilogue: restage f32 tile through LDS (stride 132), coalesced out ----
  float biasv[4];
#pragma unroll
  for (int n = 0; n < 4; ++n) {
    int c = n0 + wc * 64 + n * 16 + l16;
    biasv[n] = (bias != nullptr && c < Ncols) ? bias[c] : 0.f;
  }

  float csum = 0.f, csq = 0.f;

#pragma unroll
  for (int h = 0; h < 2; ++h) {
    __syncthreads();
    if (wr == h) {
#pragma unroll
      for (int m = 0; m < 4; ++m)
#pragma unroll
        for (int n = 0; n < 4; ++n)
#pragma unroll
          for (int r = 0; r < 4; ++r) {
            int lr = m * 16 + lg * 4 + r;  // C/D: row=(lane>>4)*4+reg, col=lane&15
            sC[lr * 132 + wc * 64 + n * 16 + l16] = acc[m][n][r] + biasv[n];
          }
    }
    __syncthreads();
    const int lr = t >> 2;
    const int cs = (t & 3) * 32;
    const float* src = sC + lr * 132 + cs;
    const int row = m0 + h * 64 + lr;
    if constexpr (EPI == 2) {
      float* rowp = (float*)outp + (size_t)row * ldOut;
#pragma unroll
      for (int j = 0; j < 32; j += 4) {
        int c = n0 + cs + j;
        if (c + 3 < Ncols) {
          *(f32x4*)(rowp + c) = *(const f32x4*)(src + j);
        } else {
#pragma unroll
          for (int e = 0; e < 4; ++e)
            if (c + e < Ncols) rowp[c + e] = src[j + e];
        }
      }
    } else {
      f16* dst = (f16*)outp + (size_t)row * ldOut + n0 + cs;
#pragma unroll
      for (int j = 0; j < 32; j += 8) {
        f32x4 v0 = *(const f32x4*)(src + j);
        f32x4 v1 = *(const f32x4*)(src + j + 4);
        half8 hv;
#pragma unroll
        for (int e = 0; e < 4; ++e) {
          hv[e] = (f16)v0[e];
          hv[4 + e] = (f16)v1[e];
        }
        *(half8*)(dst + j) = hv;
      }
    }
    if constexpr (EPI == 0) {
      if (t < 128) {
        for (int r2 = 0; r2 < 64; ++r2) {
          float v = sC[r2 * 132 + t];
          csum += v;
          csq += v * v;
        }
      }
    }
  }
  if constexpr (EPI == 0) {
    if (t < 128) partial[(size_t)by * 1024 + n0 + t] = make_float2(csum, csq);
  }
}

// ---------------------------------------------------------------------------
__global__ void bn_fin_k(const float2* __restrict__ partial, int mtiles,
                         const float* __restrict__ g, const float* __restrict__ beta,
                         f16* __restrict__ scH, f16* __restrict__ shH, float invB) {
  const int c = blockIdx.x * 256 + threadIdx.x;  // grid 4 -> 1024 cols
  float s = 0.f, q = 0.f;
  for (int mt = 0; mt < mtiles; ++mt) {
    float2 v = partial[(size_t)mt * 1024 + c];
    s += v.x;
    q += v.y;
  }
  float m = s * invB;
  float var = q * invB - m * m;
  float sc = rsqrtf(var + 1e-3f) * g[c];
  scH[c] = (f16)sc;
  shH[c] = (f16)(beta[c] - m * sc);
}

// ---------------------------------------------------------------------------
__global__ void cvt_w_k(const float* __restrict__ W, f16* __restrict__ Wp, int N, int K, int KP) {
  const int k = blockIdx.x * 256 + threadIdx.x;
  const int n = blockIdx.y;
  if (k >= KP) return;
  float v = (n < N && k < K) ? W[(size_t)n * K + k] : 0.f;
  Wp[(size_t)n * KP + k] = (f16)v;
}

__global__ void cvt_in_k(const float* __restrict__ ip, const float* __restrict__ in_,
                         const float* __restrict__ tg, f16* __restrict__ Ap,
                         f16* __restrict__ An, f16* __restrict__ Am) {
  const int col = blockIdx.x * 256 + threadIdx.x;
  const int row = blockIdx.y;
  if (col >= 320) return;
  const size_t o = (size_t)row * 320 + col;
  float vp = 0.f, vn = 0.f, vm = 0.f;
  if (col < 300) {
    vp = ip[(size_t)row * 300 + col];
    vn = in_[(size_t)row * 300 + col];
  }
  if (col >= 10 && col < 310) vm = tg[(size_t)row * 300 + (col - 10)];
  Ap[o] = (f16)vp;
  An[o] = (f16)vn;
  Am[o] = (f16)vm;
}

// --------------------------- loc branch ------------------------------------
__global__ void loc_stats_k(const float* __restrict__ lat, const float* __restrict__ lon,
                            const float* __restrict__ Wloc, const float* __restrict__ bloc,
                            float* __restrict__ partial) {
  const int t = threadIdx.x;
  const int row = blockIdx.x * 256 + t;
  float la = lat[row], lo = lon[row];
  float s[10], q[10];
#pragma unroll
  for (int j = 0; j < 10; ++j) {
    float y = la * Wloc[j * 2] + lo * Wloc[j * 2 + 1] + bloc[j];
    s[j] = y;
    q[j] = y * y;
  }
#pragma unroll
  for (int j = 0; j < 10; ++j)
    for (int off = 32; off; off >>= 1) {
      s[j] += __shfl_xor(s[j], off);
      q[j] += __shfl_xor(q[j], off);
    }
  __shared__ float red[4][20];
  const int wave = t >> 6, lane = t & 63;
  if (lane == 0) {
#pragma unroll
    for (int j = 0; j < 10; ++j) {
      red[wave][j] = s[j];
      red[wave][10 + j] = q[j];
    }
  }
  __syncthreads();
  if (t < 20) partial[blockIdx.x * 20 + t] = red[0][t] + red[1][t] + red[2][t] + red[3][t];
}

__global__ void loc_fin_k(const float* __restrict__ partial, int nblk,
                          const float* __restrict__ g, const float* __restrict__ beta,
                          float2* __restrict__ ss, float invB) {
  int t = threadIdx.x;
  if (t < 10) {
    float s = 0.f, q = 0.f;
    for (int b = 0; b < nblk; ++b) {
      s += partial[b * 20 + t];
      q += partial[b * 20 + 10 + t];
    }
    float m = s * invB;
    float var = q * invB - m * m;
    float sc = rsqrtf(var + 1e-3f) * g[t];
    ss[t] = make_float2(sc, beta[t] - m * sc);
  }
}

__global__ void loc_write_k(const float* __restrict__ lat, const float* __restrict__ lon,
                            const float* __restrict__ Wloc, const float* __restrict__ bloc,
                            const float2* __restrict__ ss, f16* __restrict__ Am) {
  const int row = blockIdx.x * 256 + threadIdx.x;
  float la = lat[row], lo = lon[row];
  f16* dst = Am + (size_t)row * 320;
#pragma unroll
  for (int j = 0; j < 10; ++j) {
    float y = la * Wloc[j * 2] + lo * Wloc[j * 2 + 1] + bloc[j];
    float2 sv = ss[j];
    dst[j] = (f16)fmaxf(y * sv.x + sv.y, 0.f);
  }
}

// --------------------------- count -----------------------------------------
__global__ void count_k(const float* __restrict__ P, const float* __restrict__ Nn,
                        const float* __restrict__ Aa, int B, int* __restrict__ cnt) {
  const int gw = (blockIdx.x * blockDim.x + threadIdx.x) >> 6;
  const int lane = threadIdx.x & 63;
  const int nw = (gridDim.x * blockDim.x) >> 6;
  int local = 0;
  for (int row = gw; row < B; row += nw) {
    const float* ar = Aa + (size_t)row * 300;
    const float* pr = P + (size_t)row * 300;
    const float* nr = Nn + (size_t)row * 300;
    float sp = 0.f, sn = 0.f;
    for (int e = lane; e < 300; e += 64) {
      float av = ar[e];
      float d1 = av - pr[e] + 1e-6f;
      float d2 = av - nr[e] + 1e-6f;
      sp += d1 * d1;
      sn += d2 * d2;
    }
#pragma unroll
    for (int off = 32; off; off >>= 1) {
      sp += __shfl_xor(sp, off);
      sn += __shfl_xor(sn, off);
    }
    if (lane == 0 && (sqrtf(sn) - sqrtf(sp) > 0.1f)) ++local;
  }
  if (lane == 0 && local) atomicAdd(cnt, local);
}

__global__ void zero_i32(int* p) {
  if (threadIdx.x == 0 && blockIdx.x == 0) *p = 0;
}
__global__ void write_cnt_k(const int* c, float* o) {
  if (threadIdx.x == 0 && blockIdx.x == 0) *o = (float)(*c);
}

// ---------------------------------------------------------------------------
extern "C" void kernel_launch(void* const* d_in, const int* in_sizes, int n_in,
                              void* d_out, int out_size, void* d_ws, size_t ws_size,
                              hipStream_t stream) {
  const float* img_p = (const float*)d_in[0];
  const float* img_n = (const float*)d_in[1];
  const float* tag = (const float*)d_in[2];
  const float* lat = (const float*)d_in[3];
  const float* lon = (const float*)d_in[4];
  const float* Wi1 = (const float*)d_in[5];
  const float* bi1 = (const float*)d_in[6];
  const float* gi1 = (const float*)d_in[7];
  const float* bti1 = (const float*)d_in[8];
  const float* Wi2 = (const float*)d_in[9];
  const float* bi2 = (const float*)d_in[10];
  const float* Wi3 = (const float*)d_in[11];
  const float* bi3 = (const float*)d_in[12];
  const float* Wloc = (const float*)d_in[13];
  const float* bloc = (const float*)d_in[14];
  const float* gloc = (const float*)d_in[15];
  const float* btloc = (const float*)d_in[16];
  const float* Wm1 = (const float*)d_in[17];
  const float* bm1 = (const float*)d_in[18];
  const float* gm1 = (const float*)d_in[19];
  const float* btm1 = (const float*)d_in[20];
  const float* Wm2 = (const float*)d_in[21];
  const float* bm2 = (const float*)d_in[22];
  const float* gm2 = (const float*)d_in[23];
  const float* btm2 = (const float*)d_in[24];
  const float* Wm3 = (const float*)d_in[25];
  const float* bm3 = (const float*)d_in[26];
  const float* gm3 = (const float*)d_in[27];
  const float* btm3 = (const float*)d_in[28];
  const float* Wm4 = (const float*)d_in[29];
  const float* bm4 = (const float*)d_in[30];

  const int B = in_sizes[3];  // lat has B elements
  const int MT = B / 128;
  float* out = (float*)d_out;
  float* outP = out;
  float* outN = out + (size_t)B * 300;
  float* outA = out + (size_t)2 * B * 300;
  float* outC = out + (size_t)3 * B * 300;

  char* w = (char*)d_ws;
  auto alloc = [&](size_t bytes) {
    char* p = w;
    w += (bytes + 255) & ~(size_t)255;
    return p;
  };
  f16* Wi1p = (f16*)alloc((size_t)1024 * 320 * 2);
  f16* Wi2p = (f16*)alloc((size_t)1024 * 1024 * 2);
  f16* Wi3p = (f16*)alloc((size_t)384 * 1024 * 2);
  f16* Wm1p = (f16*)alloc((size_t)1024 * 320 * 2);
  f16* Wm2p = (f16*)alloc((size_t)1024 * 1024 * 2);
  f16* Wm3p = (f16*)alloc((size_t)1024 * 1024 * 2);
  f16* Wm4p = (f16*)alloc((size_t)384 * 1024 * 2);
  f16* Ap = (f16*)alloc((size_t)B * 320 * 2);
  f16* An = (f16*)alloc((size_t)B * 320 * 2);
  f16* Am = (f16*)alloc((size_t)B * 320 * 2);
  f16* ACT0 = (f16*)alloc((size_t)B * 1024 * 2);
  f16* ACT1 = (f16*)alloc((size_t)B * 1024 * 2);
  float2* part = (float2*)alloc((size_t)MT * 1024 * 8);
  f16* scA = (f16*)alloc(1024 * 2);
  f16* shA = (f16*)alloc(1024 * 2);
  f16* scB = (f16*)alloc(1024 * 2);
  f16* shB = (f16*)alloc(1024 * 2);
  float* locpart = (float*)alloc((size_t)(B / 256) * 20 * 4);
  float2* locss = (float2*)alloc(16 * 8);
  int* cnt = (int*)alloc(256);
  (void)ws_size;
  (void)out_size;
  (void)n_in;

  const float invB = 1.f / (float)B;

  // weight + input conversion to padded f16
  cvt_w_k<<<dim3(2, 1024), 256, 0, stream>>>(Wi1, Wi1p, 1024, 300, 320);
  cvt_w_k<<<dim3(4, 1024), 256, 0, stream>>>(Wi2, Wi2p, 1024, 1024, 1024);
  cvt_w_k<<<dim3(4, 384), 256, 0, stream>>>(Wi3, Wi3p, 300, 1024, 1024);
  cvt_w_k<<<dim3(2, 1024), 256, 0, stream>>>(Wm1, Wm1p, 1024, 310, 320);
  cvt_w_k<<<dim3(4, 1024), 256, 0, stream>>>(Wm2, Wm2p, 1024, 1024, 1024);
  cvt_w_k<<<dim3(4, 1024), 256, 0, stream>>>(Wm3, Wm3p, 1024, 1024, 1024);
  cvt_w_k<<<dim3(4, 384), 256, 0, stream>>>(Wm4, Wm4p, 300, 1024, 1024);
  cvt_in_k<<<dim3(2, B), 256, 0, stream>>>(img_p, img_n, tag, Ap, An, Am);

  // loc branch (fills Am cols 0..9)
  loc_stats_k<<<dim3(B / 256), 256, 0, stream>>>(lat, lon, Wloc, bloc, locpart);
  loc_fin_k<<<dim3(1), 64, 0, stream>>>(locpart, B / 256, gloc, btloc, locss, invB);
  loc_write_k<<<dim3(B / 256), 256, 0, stream>>>(lat, lon, Wloc, bloc, locss, Am);

  // p branch
  gemm_k<0, 0><<<dim3(8, MT), 256, 0, stream>>>(Ap, Wi1p, 5, 320, ACT0, 1024, 1024, bi1, part, nullptr, nullptr);
  bn_fin_k<<<dim3(4), 256, 0, stream>>>(part, MT, gi1, bti1, scA, shA, invB);
  gemm_k<1, 1><<<dim3(8, MT), 256, 0, stream>>>(ACT0, Wi2p, 16, 1024, ACT1, 1024, 1024, bi2, nullptr, scA, shA);
  gemm_k<2, 0><<<dim3(3, MT), 256, 0, stream>>>(ACT1, Wi3p, 16, 1024, outP, 300, 300, bi3, nullptr, nullptr, nullptr);

  // n branch
  gemm_k<0, 0><<<dim3(8, MT), 256, 0, stream>>>(An, Wi1p, 5, 320, ACT0, 1024, 1024, bi1, part, nullptr, nullptr);
  bn_fin_k<<<dim3(4), 256, 0, stream>>>(part, MT, gi1, bti1, scA, shA, invB);
  gemm_k<1, 1><<<dim3(8, MT), 256, 0, stream>>>(ACT0, Wi2p, 16, 1024, ACT1, 1024, 1024, bi2, nullptr, scA, shA);
  gemm_k<2, 0><<<dim3(3, MT), 256, 0, stream>>>(ACT1, Wi3p, 16, 1024, outN, 300, 300, bi3, nullptr, nullptr, nullptr);

  // mm branch
  gemm_k<0, 0><<<dim3(8, MT), 256, 0, stream>>>(Am, Wm1p, 5, 320, ACT0, 1024, 1024, bm1, part, nullptr, nullptr);
  bn_fin_k<<<dim3(4), 256, 0, stream>>>(part, MT, gm1, btm1, scA, shA, invB);
  gemm_k<0, 1><<<dim3(8, MT), 256, 0, stream>>>(ACT0, Wm2p, 16, 1024, ACT1, 1024, 1024, bm2, part, scA, shA);
  bn_fin_k<<<dim3(4), 256, 0, stream>>>(part, MT, gm2, btm2, scB, shB, invB);
  gemm_k<0, 1><<<dim3(8, MT), 256, 0, stream>>>(ACT1, Wm3p, 16, 1024, ACT0, 1024, 1024, bm3, part, scB, shB);
  bn_fin_k<<<dim3(4), 256, 0, stream>>>(part, MT, gm3, btm3, scA, shA, invB);
  gemm_k<2, 1><<<dim3(3, MT), 256, 0, stream>>>(ACT0, Wm4p, 16, 1024, outA, 300, 300, bm4, nullptr, scA, shA);

  // pairwise distances + margin count
  zero_i32<<<1, 64, 0, stream>>>(cnt);
  count_k<<<dim3(256), 256, 0, stream>>>(outP, outN, outA, B, cnt);
  write_cnt_k<<<1, 64, 0, stream>>>(cnt, outC);
}

// Round 3
// 1162.276 us; speedup vs baseline: 1.2807x; 1.0922x over previous
//
#include <hip/hip_runtime.h>

typedef _Float16 f16;
typedef _Float16 half8 __attribute__((ext_vector_type(8)));
typedef float f32x4 __attribute__((ext_vector_type(4)));

__device__ __forceinline__ void gl_lds16(const void* g, void* l) {
  __builtin_amdgcn_global_load_lds(
      (__attribute__((address_space(1))) void*)(size_t)g,
      (__attribute__((address_space(3))) void*)l, 16, 0, 0);
}

// ---------------------------------------------------------------------------
// 256x256 x BK=64 GEMM, 8 waves (2Mx4N, per-wave 128x64), double-buffered LDS
// (2 x 64KB), 1 barrier per K-tile, prefetch issued before compute (T3-min).
// Grouped: tile-row ranges [0,r1) [r1,r2) [r2,..) use {Bw,bias,sc,sh} 0/1/2.
// EPI 0: f16 out + per-column stats partials.  EPI 2: f32 out, col-masked.
// BNA 1: A-fragments get fused BatchNorm+ReLU (y*sc[k]+sh[k], max 0).
// ---------------------------------------------------------------------------
template <int EPI, int BNA>
__global__ __launch_bounds__(512, 2) void gemm256_k(
    const f16* __restrict__ A, int Ksteps, int KP,
    void* __restrict__ outp, int ldOut, int Ncols,
    float2* __restrict__ partial, int r1, int r2,
    const f16* __restrict__ B0, const float* __restrict__ bias0,
    const f16* __restrict__ sc0, const f16* __restrict__ sh0,
    const f16* __restrict__ B1, const float* __restrict__ bias1,
    const f16* __restrict__ sc1, const f16* __restrict__ sh1,
    const f16* __restrict__ B2, const float* __restrict__ bias2,
    const f16* __restrict__ sc2, const f16* __restrict__ sh2) {
  __shared__ char smem[131072];

  const int t = threadIdx.x;
  const int lane = t & 63;
  const int wave = t >> 6;
  const int wm = wave >> 2, wn = wave & 3;
  const int l16 = lane & 15, lg = lane >> 4;

  // bijective XCD-chunked swizzle (all grids have nwg % 8 == 0)
  int bx = blockIdx.x, by = blockIdx.y;
  {
    const int nwg = gridDim.x * gridDim.y;
    const int wg = bx + gridDim.x * by;
    const int cpx = nwg >> 3;
    const int newid = (wg & 7) * cpx + (wg >> 3);
    bx = newid % gridDim.x;
    by = newid / gridDim.x;
  }
  const int m0 = by * 256;
  const int n0 = bx * 256;

  const f16* Bw = B0;
  const float* bias = bias0;
  const f16* scH = sc0;
  const f16* shH = sh0;
  if (by >= r2) { Bw = B2; bias = bias2; scH = sc2; shH = sh2; }
  else if (by >= r1) { Bw = B1; bias = bias1; scH = sc1; shH = sh1; }

  f32x4 acc[8][4] = {};

  const int rr = t >> 3;               // 0..63 (row within a 64-row round)
  const int ssw = (t & 7) ^ (rr & 7);  // pre-swizzled global seg (rule #21)
  const size_t rstep = (size_t)64 * KP * 2;
  const char* gA = (const char*)A + (size_t)(m0 + rr) * KP * 2 + ssw * 16;
  const char* gB = (const char*)Bw + (size_t)(n0 + rr) * KP * 2 + ssw * 16;
  char* const lA = smem + t * 16;
  char* const lB = smem + 32768 + t * 16;

  auto stage = [&](int buf, int kt) {
    const char* pA = gA + (size_t)kt * 128;
    const char* pB = gB + (size_t)kt * 128;
    char* dA = lA + buf * 65536;
    char* dB = lB + buf * 65536;
#pragma unroll
    for (int r = 0; r < 4; ++r) {
      gl_lds16(pA, dA + r * 8192);
      gl_lds16(pB, dB + r * 8192);
      pA += rstep;
      pB += rstep;
    }
  };

  stage(0, 0);
  __syncthreads();  // compiler drains vmcnt(0) here

  for (int kt = 0; kt < Ksteps; ++kt) {
    const int cur = kt & 1;
    if (kt + 1 < Ksteps) stage(cur ^ 1, kt + 1);  // prefetch overlaps compute
    const char* bufA = smem + cur * 65536;
    const char* bufB = bufA + 32768;
#pragma unroll
    for (int kk = 0; kk < 2; ++kk) {
      const int segx = (kk << 2) | lg;
      half8 af[8], bf[4];
#pragma unroll
      for (int m = 0; m < 8; ++m) {
        const int row = wm * 128 + m * 16 + l16;
        af[m] = *(const half8*)(bufA + row * 128 + ((segx ^ (row & 7)) << 4));
      }
#pragma unroll
      for (int n = 0; n < 4; ++n) {
        const int row = wn * 64 + n * 16 + l16;
        bf[n] = *(const half8*)(bufB + row * 128 + ((segx ^ (row & 7)) << 4));
      }
      if constexpr (BNA) {
        const int kb = kt * 64 + kk * 32 + lg * 8;
        const half8 scv = *(const half8*)(scH + kb);
        const half8 shv = *(const half8*)(shH + kb);
        const half8 zeroh = {};
#pragma unroll
        for (int m = 0; m < 8; ++m)
          af[m] = __builtin_elementwise_max((half8)(af[m] * scv + shv), zeroh);
      }
#pragma unroll
      for (int m = 0; m < 8; ++m)
#pragma unroll
        for (int n = 0; n < 4; ++n)
          acc[m][n] = __builtin_amdgcn_mfma_f32_16x16x32_f16(af[m], bf[n], acc[m][n], 0, 0, 0);
    }
    __syncthreads();  // next-tile loads drained; buffers flip
  }

  // ---- epilogue: per-wave LDS restage (no barriers), bias + stats fused ----
  float* const swv = (float*)smem + wave * 1152;  // 16 x 68 f32 per wave
  float biasv[4];
#pragma unroll
  for (int n = 0; n < 4; ++n) {
    const int c = n0 + wn * 64 + n * 16 + l16;
    biasv[n] = (bias != nullptr && c < Ncols) ? bias[c] : 0.f;
  }
  float cs[4] = {}, cq[4] = {};
  const int rowr = lane >> 2;
  const int colc = (lane & 3) << 4;

#pragma unroll
  for (int m = 0; m < 8; ++m) {
#pragma unroll
    for (int n = 0; n < 4; ++n)
#pragma unroll
      for (int r = 0; r < 4; ++r) {
        const float v = acc[m][n][r] + biasv[n];
        swv[(lg * 4 + r) * 68 + n * 16 + l16] = v;
        if constexpr (EPI == 0) {
          cs[n] += v;
          cq[n] += v * v;
        }
      }
    asm volatile("s_waitcnt lgkmcnt(0)" ::: "memory");
    const float* sp = swv + rowr * 68 + colc;
    const int grow = m0 + wm * 128 + m * 16 + rowr;
    if constexpr (EPI == 2) {
      float* rp = (float*)outp + (size_t)grow * ldOut;
#pragma unroll
      for (int j = 0; j < 4; ++j) {
        const int c = n0 + wn * 64 + colc + j * 4;
        const f32x4 v = *(const f32x4*)(sp + j * 4);
        if (c + 3 < Ncols) {
          *(f32x4*)(rp + c) = v;
        } else {
#pragma unroll
          for (int e = 0; e < 4; ++e)
            if (c + e < Ncols) rp[c + e] = v[e];
        }
      }
    } else {
      f16* dp = (f16*)outp + (size_t)grow * ldOut + n0 + wn * 64 + colc;
      half8 h0, h1;
#pragma unroll
      for (int e = 0; e < 4; ++e) {
        h0[e] = (f16)sp[e];
        h0[4 + e] = (f16)sp[4 + e];
        h1[e] = (f16)sp[8 + e];
        h1[4 + e] = (f16)sp[12 + e];
      }
      *(half8*)dp = h0;
      *(half8*)(dp + 8) = h1;
    }
    asm volatile("s_waitcnt lgkmcnt(0)" ::: "memory");  // reads done before next slice
  }

  if constexpr (EPI == 0) {
#pragma unroll
    for (int n = 0; n < 4; ++n) {
      cs[n] += __shfl_xor(cs[n], 16);
      cs[n] += __shfl_xor(cs[n], 32);
      cq[n] += __shfl_xor(cq[n], 16);
      cq[n] += __shfl_xor(cq[n], 32);
    }
    if (lane < 16) {
      float2* pp = partial + (size_t)(by * 2 + wm) * 1024 + n0 + wn * 64 + lane;
#pragma unroll
      for (int n = 0; n < 4; ++n) pp[n * 16] = make_float2(cs[n], cq[n]);
    }
  }
}

// ---------------------------------------------------------------------------
__global__ void bn_fin_k(const float2* __restrict__ partial, int rowStart, int nrows,
                         const float* __restrict__ g, const float* __restrict__ beta,
                         f16* __restrict__ scH, f16* __restrict__ shH, float invB) {
  const int c = blockIdx.x * 256 + threadIdx.x;  // grid 4 -> 1024 cols
  float s = 0.f, q = 0.f;
  const float2* p = partial + (size_t)rowStart * 1024 + c;
  for (int i = 0; i < nrows; ++i) {
    float2 v = p[(size_t)i * 1024];
    s += v.x;
    q += v.y;
  }
  float m = s * invB;
  float var = q * invB - m * m;
  float sc = rsqrtf(var + 1e-3f) * g[c];
  scH[c] = (f16)sc;
  shH[c] = (f16)(beta[c] - m * sc);
}

// ---------------------------------------------------------------------------
__global__ void cvt_w_k(const float* __restrict__ W, f16* __restrict__ Wp, int N, int K, int KP) {
  const int k = blockIdx.x * 256 + threadIdx.x;
  const int n = blockIdx.y;
  if (k >= KP) return;
  float v = (n < N && k < K) ? W[(size_t)n * K + k] : 0.f;
  Wp[(size_t)n * KP + k] = (f16)v;
}

__global__ void cvt_in_k(const float* __restrict__ ip, const float* __restrict__ in_,
                         const float* __restrict__ tg, f16* __restrict__ Ap,
                         f16* __restrict__ An, f16* __restrict__ Am) {
  const int col = blockIdx.x * 256 + threadIdx.x;
  const int row = blockIdx.y;
  if (col >= 320) return;
  const size_t o = (size_t)row * 320 + col;
  float vp = 0.f, vn = 0.f, vm = 0.f;
  if (col < 300) {
    vp = ip[(size_t)row * 300 + col];
    vn = in_[(size_t)row * 300 + col];
  }
  if (col >= 10 && col < 310) vm = tg[(size_t)row * 300 + (col - 10)];
  Ap[o] = (f16)vp;
  An[o] = (f16)vn;
  Am[o] = (f16)vm;
}

// --------------------------- loc branch ------------------------------------
__global__ void loc_stats_k(const float* __restrict__ lat, const float* __restrict__ lon,
                            const float* __restrict__ Wloc, const float* __restrict__ bloc,
                            float* __restrict__ partial) {
  const int t = threadIdx.x;
  const int row = blockIdx.x * 256 + t;
  float la = lat[row], lo = lon[row];
  float s[10], q[10];
#pragma unroll
  for (int j = 0; j < 10; ++j) {
    float y = la * Wloc[j * 2] + lo * Wloc[j * 2 + 1] + bloc[j];
    s[j] = y;
    q[j] = y * y;
  }
#pragma unroll
  for (int j = 0; j < 10; ++j)
    for (int off = 32; off; off >>= 1) {
      s[j] += __shfl_xor(s[j], off);
      q[j] += __shfl_xor(q[j], off);
    }
  __shared__ float red[4][20];
  const int wave = t >> 6, lane = t & 63;
  if (lane == 0) {
#pragma unroll
    for (int j = 0; j < 10; ++j) {
      red[wave][j] = s[j];
      red[wave][10 + j] = q[j];
    }
  }
  __syncthreads();
  if (t < 20) partial[blockIdx.x * 20 + t] = red[0][t] + red[1][t] + red[2][t] + red[3][t];
}

__global__ void loc_fin_k(const float* __restrict__ partial, int nblk,
                          const float* __restrict__ g, const float* __restrict__ beta,
                          float2* __restrict__ ss, float invB) {
  int t = threadIdx.x;
  if (t < 10) {
    float s = 0.f, q = 0.f;
    for (int b = 0; b < nblk; ++b) {
      s += partial[b * 20 + t];
      q += partial[b * 20 + 10 + t];
    }
    float m = s * invB;
    float var = q * invB - m * m;
    float sc = rsqrtf(var + 1e-3f) * g[t];
    ss[t] = make_float2(sc, beta[t] - m * sc);
  }
}

__global__ void loc_write_k(const float* __restrict__ lat, const float* __restrict__ lon,
                            const float* __restrict__ Wloc, const float* __restrict__ bloc,
                            const float2* __restrict__ ss, f16* __restrict__ Am) {
  const int row = blockIdx.x * 256 + threadIdx.x;
  float la = lat[row], lo = lon[row];
  f16* dst = Am + (size_t)row * 320;
#pragma unroll
  for (int j = 0; j < 10; ++j) {
    float y = la * Wloc[j * 2] + lo * Wloc[j * 2 + 1] + bloc[j];
    float2 sv = ss[j];
    dst[j] = (f16)fmaxf(y * sv.x + sv.y, 0.f);
  }
}

// --------------------------- count -----------------------------------------
__global__ void count_k(const float* __restrict__ P, const float* __restrict__ Nn,
                        const float* __restrict__ Aa, int B, int* __restrict__ cnt) {
  const int gw = (blockIdx.x * blockDim.x + threadIdx.x) >> 6;
  const int lane = threadIdx.x & 63;
  const int nw = (gridDim.x * blockDim.x) >> 6;
  int local = 0;
  for (int row = gw; row < B; row += nw) {
    const float* ar = Aa + (size_t)row * 300;
    const float* pr = P + (size_t)row * 300;
    const float* nr = Nn + (size_t)row * 300;
    float sp = 0.f, sn = 0.f;
    for (int e = lane; e < 300; e += 64) {
      float av = ar[e];
      float d1 = av - pr[e] + 1e-6f;
      float d2 = av - nr[e] + 1e-6f;
      sp += d1 * d1;
      sn += d2 * d2;
    }
#pragma unroll
    for (int off = 32; off; off >>= 1) {
      sp += __shfl_xor(sp, off);
      sn += __shfl_xor(sn, off);
    }
    if (lane == 0 && (sqrtf(sn) - sqrtf(sp) > 0.1f)) ++local;
  }
  if (lane == 0 && local) atomicAdd(cnt, local);
}

__global__ void zero_i32(int* p) {
  if (threadIdx.x == 0 && blockIdx.x == 0) *p = 0;
}
__global__ void write_cnt_k(const int* c, float* o) {
  if (threadIdx.x == 0 && blockIdx.x == 0) *o = (float)(*c);
}

// ---------------------------------------------------------------------------
extern "C" void kernel_launch(void* const* d_in, const int* in_sizes, int n_in,
                              void* d_out, int out_size, void* d_ws, size_t ws_size,
                              hipStream_t stream) {
  const float* img_p = (const float*)d_in[0];
  const float* img_n = (const float*)d_in[1];
  const float* tag = (const float*)d_in[2];
  const float* lat = (const float*)d_in[3];
  const float* lon = (const float*)d_in[4];
  const float* Wi1 = (const float*)d_in[5];
  const float* bi1 = (const float*)d_in[6];
  const float* gi1 = (const float*)d_in[7];
  const float* bti1 = (const float*)d_in[8];
  const float* Wi2 = (const float*)d_in[9];
  const float* bi2 = (const float*)d_in[10];
  const float* Wi3 = (const float*)d_in[11];
  const float* bi3 = (const float*)d_in[12];
  const float* Wloc = (const float*)d_in[13];
  const float* bloc = (const float*)d_in[14];
  const float* gloc = (const float*)d_in[15];
  const float* btloc = (const float*)d_in[16];
  const float* Wm1 = (const float*)d_in[17];
  const float* bm1 = (const float*)d_in[18];
  const float* gm1 = (const float*)d_in[19];
  const float* btm1 = (const float*)d_in[20];
  const float* Wm2 = (const float*)d_in[21];
  const float* bm2 = (const float*)d_in[22];
  const float* gm2 = (const float*)d_in[23];
  const float* btm2 = (const float*)d_in[24];
  const float* Wm3 = (const float*)d_in[25];
  const float* bm3 = (const float*)d_in[26];
  const float* gm3 = (const float*)d_in[27];
  const float* btm3 = (const float*)d_in[28];
  const float* Wm4 = (const float*)d_in[29];
  const float* bm4 = (const float*)d_in[30];

  const int B = in_sizes[3];  // 32768
  float* out = (float*)d_out;
  float* outP = out;
  float* outN = out + (size_t)B * 300;
  float* outA = out + (size_t)2 * B * 300;
  float* outC = out + (size_t)3 * B * 300;

  char* w = (char*)d_ws;
  auto alloc = [&](size_t bytes) {
    char* p = w;
    w += (bytes + 255) & ~(size_t)255;
    return p;
  };

  // common allocations
  f16* Wi1p = (f16*)alloc((size_t)1024 * 320 * 2);
  f16* Wi2p = (f16*)alloc((size_t)1024 * 1024 * 2);
  f16* Wi3p = (f16*)alloc((size_t)512 * 1024 * 2);
  f16* Wm1p = (f16*)alloc((size_t)1024 * 320 * 2);
  f16* Wm2p = (f16*)alloc((size_t)1024 * 1024 * 2);
  f16* Wm3p = (f16*)alloc((size_t)1024 * 1024 * 2);
  f16* Wm4p = (f16*)alloc((size_t)512 * 1024 * 2);
  f16* ssT = (f16*)alloc(10 * 1024 * 2);  // 5 (sc,sh) pairs of f16[1024]
  f16 *scP1 = ssT, *shP1 = ssT + 1024, *scN1 = ssT + 2048, *shN1 = ssT + 3072;
  f16 *scM1 = ssT + 4096, *shM1 = ssT + 5120, *scM2 = ssT + 6144, *shM2 = ssT + 7168;
  f16 *scM3 = ssT + 8192, *shM3 = ssT + 9216;
  float* locpart = (float*)alloc((size_t)(B / 256) * 20 * 4);
  float2* locss = (float2*)alloc(16 * 8);
  int* cnt = (int*)alloc(256);
  f16* Ain = (f16*)alloc((size_t)3 * B * 320 * 2);  // [p; n; m] inputs
  f16 *Ap = Ain, *An = Ain + (size_t)B * 320, *Am = Ain + (size_t)2 * B * 320;

  const size_t used_common = (size_t)(w - (char*)d_ws);
  const size_t fusedNeed =
      used_common + 2 * ((size_t)3 * B * 1024 * 2) + (size_t)(3 * B / 256) * 2 * 1024 * 8 + (1u << 20);
  const bool fused = ws_size >= fusedNeed;

  const size_t actRows = fused ? (size_t)3 * B : (size_t)B;
  f16* ACT0 = (f16*)alloc(actRows * 1024 * 2);
  f16* ACT1 = (f16*)alloc(actRows * 1024 * 2);
  float2* part = (float2*)alloc((size_t)(fused ? (3 * B / 128) : (B / 128)) * 1024 * 8);
  (void)out_size;
  (void)n_in;

  const float invB = 1.f / (float)B;
  const int BIG = 1 << 30;

  // weight + input conversion to padded f16
  cvt_w_k<<<dim3(2, 1024), 256, 0, stream>>>(Wi1, Wi1p, 1024, 300, 320);
  cvt_w_k<<<dim3(4, 1024), 256, 0, stream>>>(Wi2, Wi2p, 1024, 1024, 1024);
  cvt_w_k<<<dim3(4, 512), 256, 0, stream>>>(Wi3, Wi3p, 300, 1024, 1024);
  cvt_w_k<<<dim3(2, 1024), 256, 0, stream>>>(Wm1, Wm1p, 1024, 310, 320);
  cvt_w_k<<<dim3(4, 1024), 256, 0, stream>>>(Wm2, Wm2p, 1024, 1024, 1024);
  cvt_w_k<<<dim3(4, 1024), 256, 0, stream>>>(Wm3, Wm3p, 1024, 1024, 1024);
  cvt_w_k<<<dim3(4, 512), 256, 0, stream>>>(Wm4, Wm4p, 300, 1024, 1024);
  cvt_in_k<<<dim3(2, B), 256, 0, stream>>>(img_p, img_n, tag, Ap, An, Am);

  // loc branch (fills Am cols 0..9)
  loc_stats_k<<<dim3(B / 256), 256, 0, stream>>>(lat, lon, Wloc, bloc, locpart);
  loc_fin_k<<<dim3(1), 64, 0, stream>>>(locpart, B / 256, gloc, btloc, locss, invB);
  loc_write_k<<<dim3(B / 256), 256, 0, stream>>>(lat, lon, Wloc, bloc, locss, Am);

  const int MT = B / 256;  // 128 y-tiles per branch

  if (fused) {
    // S1: [p;n;m] layer-1 (K=320), grouped weights, stats per branch range
    gemm256_k<0, 0><<<dim3(4, 3 * MT), 512, 0, stream>>>(
        Ain, 5, 320, ACT0, 1024, 1024, part, MT, 2 * MT,
        Wi1p, bi1, nullptr, nullptr, Wi1p, bi1, nullptr, nullptr, Wm1p, bm1, nullptr, nullptr);
    bn_fin_k<<<dim3(4), 256, 0, stream>>>(part, 0, 2 * MT, gi1, bti1, scP1, shP1, invB);
    bn_fin_k<<<dim3(4), 256, 0, stream>>>(part, 2 * MT, 2 * MT, gi1, bti1, scN1, shN1, invB);
    bn_fin_k<<<dim3(4), 256, 0, stream>>>(part, 4 * MT, 2 * MT, gm1, btm1, scM1, shM1, invB);
    // S2: layer-2, BN+ReLU fused on A, grouped
    gemm256_k<0, 1><<<dim3(4, 3 * MT), 512, 0, stream>>>(
        ACT0, 16, 1024, ACT1, 1024, 1024, part, MT, 2 * MT,
        Wi2p, bi2, scP1, shP1, Wi2p, bi2, scN1, shN1, Wm2p, bm2, scM1, shM1);
    bn_fin_k<<<dim3(4), 256, 0, stream>>>(part, 4 * MT, 2 * MT, gm2, btm2, scM2, shM2, invB);
    // S3a: img layer-3 for p and n in one dispatch (rows contiguous in d_out)
    gemm256_k<2, 0><<<dim3(2, 2 * MT), 512, 0, stream>>>(
        ACT1, 16, 1024, outP, 300, 300, part, BIG, BIG,
        Wi3p, bi3, nullptr, nullptr, Wi3p, bi3, nullptr, nullptr, Wi3p, bi3, nullptr, nullptr);
    // S3b: mm layer-3 (BN(scM2) on A), stats for BN3
    gemm256_k<0, 1><<<dim3(4, MT), 512, 0, stream>>>(
        ACT1 + (size_t)2 * B * 1024, 16, 1024, ACT0, 1024, 1024, part, BIG, BIG,
        Wm3p, bm3, scM2, shM2, Wm3p, bm3, scM2, shM2, Wm3p, bm3, scM2, shM2);
    bn_fin_k<<<dim3(4), 256, 0, stream>>>(part, 0, 2 * MT, gm3, btm3, scM3, shM3, invB);
    // S4: mm layer-4 -> outA
    gemm256_k<2, 1><<<dim3(2, MT), 512, 0, stream>>>(
        ACT0, 16, 1024, outA, 300, 300, part, BIG, BIG,
        Wm4p, bm4, scM3, shM3, Wm4p, bm4, scM3, shM3, Wm4p, bm4, scM3, shM3);
  } else {
    // per-branch fallback (same kernels, r2-sized footprint)
    for (int br = 0; br < 2; ++br) {
      const f16* Ax = br ? An : Ap;
      float* outX = br ? outN : outP;
      gemm256_k<0, 0><<<dim3(4, MT), 512, 0, stream>>>(
          Ax, 5, 320, ACT0, 1024, 1024, part, BIG, BIG,
          Wi1p, bi1, nullptr, nullptr, Wi1p, bi1, nullptr, nullptr, Wi1p, bi1, nullptr, nullptr);
      bn_fin_k<<<dim3(4), 256, 0, stream>>>(part, 0, 2 * MT, gi1, bti1, scP1, shP1, invB);
      gemm256_k<0, 1><<<dim3(4, MT), 512, 0, stream>>>(
          ACT0, 16, 1024, ACT1, 1024, 1024, part, BIG, BIG,
          Wi2p, bi2, scP1, shP1, Wi2p, bi2, scP1, shP1, Wi2p, bi2, scP1, shP1);
      gemm256_k<2, 0><<<dim3(2, MT), 512, 0, stream>>>(
          ACT1, 16, 1024, outX, 300, 300, part, BIG, BIG,
          Wi3p, bi3, nullptr, nullptr, Wi3p, bi3, nullptr, nullptr, Wi3p, bi3, nullptr, nullptr);
    }
    gemm256_k<0, 0><<<dim3(4, MT), 512, 0, stream>>>(
        Am, 5, 320, ACT0, 1024, 1024, part, BIG, BIG,
        Wm1p, bm1, nullptr, nullptr, Wm1p, bm1, nullptr, nullptr, Wm1p, bm1, nullptr, nullptr);
    bn_fin_k<<<dim3(4), 256, 0, stream>>>(part, 0, 2 * MT, gm1, btm1, scM1, shM1, invB);
    gemm256_k<0, 1><<<dim3(4, MT), 512, 0, stream>>>(
        ACT0, 16, 1024, ACT1, 1024, 1024, part, BIG, BIG,
        Wm2p, bm2, scM1, shM1, Wm2p, bm2, scM1, shM1, Wm2p, bm2, scM1, shM1);
    bn_fin_k<<<dim3(4), 256, 0, stream>>>(part, 0, 2 * MT, gm2, btm2, scM2, shM2, invB);
    gemm256_k<0, 1><<<dim3(4, MT), 512, 0, stream>>>(
        ACT1, 16, 1024, ACT0, 1024, 1024, part, BIG, BIG,
        Wm3p, bm3, scM2, shM2, Wm3p, bm3, scM2, shM2, Wm3p, bm3, scM2, shM2);
    bn_fin_k<<<dim3(4), 256, 0, stream>>>(part, 0, 2 * MT, gm3, btm3, scM3, shM3, invB);
    gemm256_k<2, 1><<<dim3(2, MT), 512, 0, stream>>>(
        ACT0, 16, 1024, outA, 300, 300, part, BIG, BIG,
        Wm4p, bm4, scM3, shM3, Wm4p, bm4, scM3, shM3, Wm4p, bm4, scM3, shM3);
  }

  // pairwise distances + margin count
  zero_i32<<<1, 64, 0, stream>>>(cnt);
  count_k<<<dim3(256), 256, 0, stream>>>(outP, outN, outA, B, cnt);
  write_cnt_k<<<1, 64, 0, stream>>>(cnt, outC);
}